// Round 17
// baseline (137.020 us; speedup 1.0000x reference)
//
#include <hip/hip_runtime.h>

// ---------------- problem constants ----------------
#define B_     32
#define C_     2
#define L_     160000
#define HOP    512
#define PAD    1024
#define LPAD   162048            // L_ + 2*PAD
#define T_     313               // frames
#define BC     64                // B_*C_
#define M_     20032             // BC*T_
#define KCH    1025              // output channels per (real|imag)
#define OUT_HALF 20532800UL      // M_*KCH
#define PL     81024             // plane length per bc (LPAD/2)
#define KD     1024              // decimated K
#define NKT    32                // KD/32 K-tiles
#define NWG    1280              // 160*8 (24 dead blocks early-exit)
#define ZROW   132               // epilogue zone row stride (shorts): 264B
#define ZPL    8448              // plane offset within zone (shorts): 64*132
#define ZH     16896             // zone stride (shorts): 2*8448
#define PREP_PLANE_BLOCKS 2532   // prep grid split

typedef __attribute__((ext_vector_type(8))) short short8;
typedef __attribute__((ext_vector_type(4))) float f32x4;

static __device__ __forceinline__ short f2bf(float f) {
  union { float f; unsigned u; } v; v.f = f;
  unsigned u = v.u;
  unsigned r = (u + 0x7fffu + ((u >> 16) & 1u)) >> 16;  // RNE
  return (short)r;
}
static __device__ __forceinline__ float bf2f(unsigned s) {
  union { unsigned u; float f; } v; v.u = s << 16; return v.f;
}

// ---------------- fused prep: planes + weights in one launch ----------------
__global__ void prep_all(const float* __restrict__ x,
                         short* __restrict__ pl0, short* __restrict__ pl1,
                         short* __restrict__ wb0, short* __restrict__ wb1) {
  int b = blockIdx.x;
  if (b < PREP_PLANE_BLOCKS) {
    // ---- even/odd deinterleaved reflect-padded planes ----
    int v = b * 256 + threadIdx.x;                  // < 64*10128 = 648192
    int bc = v / 10128;
    int r  = v - bc * 10128;
    int p0 = r * 8;                                 // 8 p-positions -> 16 samples
    const float* src = x + (size_t)bc * L_;
    short8 e, o;
    if (r >= 64 && r <= 10000) {                    // fully interior
      int j0 = 16 * r - 1024;
      #pragma unroll
      for (int qq = 0; qq < 4; ++qq) {
        float4 f = *(const float4*)(src + j0 + qq * 4);
        e[qq * 2 + 0] = f2bf(f.x); o[qq * 2 + 0] = f2bf(f.y);
        e[qq * 2 + 1] = f2bf(f.z); o[qq * 2 + 1] = f2bf(f.w);
      }
    } else {
      #pragma unroll
      for (int u = 0; u < 16; ++u) {
        int j = 16 * r + u - 1024;
        j = j < 0 ? -j : j;
        j = j >= L_ ? 2 * L_ - 2 - j : j;
        short bb = f2bf(src[j]);
        if (u & 1) o[u >> 1] = bb; else e[u >> 1] = bb;
      }
    }
    *(short8*)&pl0[(size_t)bc * PL + p0] = e;
    *(short8*)&pl1[(size_t)bc * PL + p0] = o;
  } else {
    // ---- windowed DFT-1024 weights, interleaved re/im rows ----
    int id = (b - PREP_PLANE_BLOCKS) * 256 + threadIdx.x;  // < 262144
    int s   = id >> 17;
    int row = (id >> 7) & 1023;
    int n8  = (id & 127) * 8;
    int kp  = row >> 1, e = row & 1;
    short8 ov;
    #pragma unroll
    for (int u = 0; u < 8; ++u) {
      int n1 = n8 + u;
      float win = 0.5f - 0.5f * cosf((float)(2 * n1 + s) * 3.0679615757712823e-3f);
      float tw;
      if (e == 0)       tw = cosf((float)((n1 * kp) & 1023) * 6.1359231515425649e-3f);
      else if (kp == 0) tw = (n1 & 1) ? -1.0f : 1.0f;     // cos(pi*n1): re[512] row
      else              tw = -sinf((float)((n1 * kp) & 1023) * 6.1359231515425649e-3f);
      ov[u] = f2bf(win * tw);
    }
    short* wb = s ? wb1 : wb0;
    *(short8*)&wb[(size_t)row * KD + n8] = ov;
  }
}

// ---------------- GEMM: 128x128 tile, 512 thr, dual-plane acc, BK=32 ----------------
#define GLOAD16(g, l) __builtin_amdgcn_global_load_lds(                        \
    (const __attribute__((address_space(1))) void*)(g),                        \
    (__attribute__((address_space(3))) void*)(l), 16, 0, 0)

__global__ __launch_bounds__(512, 4) void stft_gemm(const short* __restrict__ pl0,
                                                    const short* __restrict__ pl1,
                                                    const short* __restrict__ wb0,
                                                    const short* __restrict__ wb1,
                                                    float* __restrict__ out) {
  // main loop: 2 buffers x (A0,A1,B0,B1 each [128][32] = 8KB) = 64KB
  // epilogue reuse: bf16 zones [2 half][2 pl][64 rows][132] = 67584 B
  __shared__ __align__(16) char lds[67584];
  const int tid  = threadIdx.x;
  const int lane = tid & 63;
  const int wid  = tid >> 6;          // 0..7

  // ---- XCD remap: 8 nt-blocks sharing an A-panel are consecutive ids with the
  // same id%8 -> same XCD -> A fetched ~once per panel; B (4MB) L2-resident.
  const int id = blockIdx.x;                   // 0..1279
  const int mt = (id & 7) * 20 + (id >> 6);    // 0..159
  if (mt >= 157) return;                       // dead-padded blocks: exit early
  const int nt = (id >> 3) & 7;
  const int M0 = mt * 128, N0 = nt * 128;

  // ---- staging: 1 instr per operand per plane; 512 threads cover [128][32] ----
  const int srow = tid >> 2;                                 // 0..127
  const int chunkSwz = ((tid & 3) ^ ((tid >> 3) & 3)) * 8;   // inverse-swizzled src
  const short* aP[2];
  const short* bP[2];
  {
    int m = M0 + srow; if (m > M_ - 1) m = M_ - 1;           // clamp (not stored)
    int bc = m / T_;
    int t  = m - bc * T_;
    size_t base = (size_t)bc * PL + (size_t)t * 256 + chunkSwz;
    aP[0] = pl0 + base;
    aP[1] = pl1 + base;
    size_t bb = (size_t)(N0 + srow) * KD + chunkSwz;
    bP[0] = wb0 + bb;
    bP[1] = wb1 + bb;
  }
  const int dstOff = tid * 16;   // linear LDS dest (waveBase + lane*16 invariant)

  // ---- fragment read offsets (proven conflict-free 64B-row XOR pattern) ----
  const int wr = wid >> 2, wc = wid & 3;    // 2m x 4n waves; per-wave 64x32
  const int fr = lane & 15;
  const int xorb = ((lane >> 4) * 16) ^ ((fr & 6) << 3);
  int afOff[2][4], bfOff[2][2];
  #pragma unroll
  for (int s = 0; s < 2; ++s) {
    #pragma unroll
    for (int i = 0; i < 4; ++i)
      afOff[s][i] = s * 8192 + (wr * 64 + i * 16 + fr) * 64 + xorb;
    #pragma unroll
    for (int j = 0; j < 2; ++j)
      bfOff[s][j] = 16384 + s * 8192 + (wc * 32 + j * 16 + fr) * 64 + xorb;
  }

  f32x4 acc[2][4][2];
  #pragma unroll
  for (int s = 0; s < 2; ++s)
    #pragma unroll
    for (int i = 0; i < 4; ++i)
      #pragma unroll
      for (int j = 0; j < 2; ++j) acc[s][i][j] = (f32x4){0.f, 0.f, 0.f, 0.f};

  // ---- prologue: stage kt=0 (A0,B0 then A1,B1 — order matters for vmcnt) ----
  GLOAD16(aP[0], lds + dstOff);
  GLOAD16(bP[0], lds + 16384 + dstOff);
  GLOAD16(aP[1], lds + 8192 + dstOff);
  GLOAD16(bP[1], lds + 24576 + dstOff);

  // ---- main loop (r16-proven): all 4 next-tile loads staged at s0; counted vmcnt ----
  for (int kt = 0; kt < NKT; ++kt) {
    char* bufR = lds + (kt & 1) * 32768;
    char* bufW = lds + ((kt + 1) & 1) * 32768;
    const int kos = (kt + 1) * 32;
    const bool st = (kt < NKT - 1);

    // phase s=0
    asm volatile("s_waitcnt vmcnt(2)" ::: "memory");   // A0,B0(kt) landed
    __builtin_amdgcn_s_barrier();
    if (st) {
      GLOAD16(aP[0] + kos, bufW + dstOff);
      GLOAD16(bP[0] + kos, bufW + 16384 + dstOff);
      GLOAD16(aP[1] + kos, bufW + 8192 + dstOff);
      GLOAD16(bP[1] + kos, bufW + 24576 + dstOff);
    }
    short8 af0[4], bf0[2];
    #pragma unroll
    for (int i = 0; i < 4; ++i) af0[i] = *(const short8*)(bufR + afOff[0][i]);
    #pragma unroll
    for (int j = 0; j < 2; ++j) bf0[j] = *(const short8*)(bufR + bfOff[0][j]);
    #pragma unroll
    for (int i = 0; i < 4; ++i)
      #pragma unroll
      for (int j = 0; j < 2; ++j)
        acc[0][i][j] = __builtin_amdgcn_mfma_f32_16x16x32_bf16(af0[i], bf0[j],
                                                               acc[0][i][j], 0, 0, 0);

    // phase s=1 (pure read+MFMA; stage already issued)
    if (st) asm volatile("s_waitcnt vmcnt(4)" ::: "memory");  // A1,B1(kt) landed
    else    asm volatile("s_waitcnt vmcnt(0)" ::: "memory");
    __builtin_amdgcn_s_barrier();
    short8 af1[4], bf1[2];
    #pragma unroll
    for (int i = 0; i < 4; ++i) af1[i] = *(const short8*)(bufR + afOff[1][i]);
    #pragma unroll
    for (int j = 0; j < 2; ++j) bf1[j] = *(const short8*)(bufR + bfOff[1][j]);
    #pragma unroll
    for (int i = 0; i < 4; ++i)
      #pragma unroll
      for (int j = 0; j < 2; ++j)
        acc[1][i][j] = __builtin_amdgcn_mfma_f32_16x16x32_bf16(af1[i], bf1[j],
                                                               acc[1][i][j], 0, 0, 0);
  }

  // ---- epilogue v5: parallel bf16 stage (both halves at once), 2 syncs ----
  // zone layout (shorts): Lz[h*ZH + pl*ZPL + row*ZROW + col], col 0..127
  // (even=re, odd=im). Stage: 2-way bank alias (free). Combine: u32 reads,
  // 256B contiguous per wave (conflict-free).
  unsigned short* Lz = (unsigned short*)lds;
  float* outI = out + OUT_HALF;
  const int q = lane;                               // 0..63 (local q index)
  const float ang = (float)(nt * 64 + q) * 3.0679615757712823e-3f;   // pi*k/1024
  const float tr = cosf(ang), sn = sinf(ang);       // t = tr - i*sn
  const int rgrp = (lane >> 4) << 2;

  __syncthreads();   // all main-loop LDS reads complete before reuse

  // stage: every wave writes its own rows into its own zone (wr = row-half)
  #pragma unroll
  for (int pl = 0; pl < 2; ++pl)
    #pragma unroll
    for (int i = 0; i < 4; ++i)
      #pragma unroll
      for (int j = 0; j < 2; ++j)
        #pragma unroll
        for (int r = 0; r < 4; ++r)
          Lz[wr * ZH + pl * ZPL + (i * 16 + rgrp + r) * ZROW + wc * 32 + j * 16 + fr]
             = (unsigned short)f2bf(acc[pl][i][j][r]);
  __syncthreads();

  // combine + store: lane = q, 16 row-iterations cover rows 0..127
  #pragma unroll
  for (int it = 0; it < 16; ++it) {
    int row = wid + it * 8;                         // 0..127
    int gm  = M0 + row;
    if (gm < M_) {
      int zb = (row >> 6) * ZH + (row & 63) * ZROW + 2 * q;
      unsigned w0 = *(const unsigned*)&Lz[zb];            // plane0 (re,im)
      unsigned w1 = *(const unsigned*)&Lz[zb + ZPL];      // plane1 (re,im)
      float y0x = bf2f(w0 & 0xffffu), y0y = bf2f(w0 >> 16);
      float y1x = bf2f(w1 & 0xffffu), y1y = bf2f(w1 >> 16);
      float ur = tr * y1x + sn * y1y;               // Re(t*Y1)
      float ui = tr * y1y - sn * y1x;               // Im(t*Y1)
      size_t rb = (size_t)gm * KCH;
      if (nt == 0 && q == 0) {
        // cols 0,1 are the special real rows: Y[0] and Y[512]
        out [rb + 0]    = y0x + y1x;                // X[0] = Y0[0]+Y1[0]
        outI[rb + 0]    = 0.f;
        out [rb + 1024] = y0x - y1x;                // X[1024] = Y0[0]-Y1[0]
        outI[rb + 1024] = 0.f;
        out [rb + 512]  = y0y;                      // X[512] = Y0[512] - i*Y1[512]
        outI[rb + 512]  = -y1y;
      } else {
        int kq = nt * 64 + q;
        out [rb + kq]        = y0x + ur;            // X[k]
        outI[rb + kq]        = y0y + ui;
        out [rb + 1024 - kq] = y0x - ur;            // X[1024-k] (conj pair)
        outI[rb + 1024 - kq] = -(y0y - ui);
      }
    }
  }
}

// ---------------- launcher ----------------
extern "C" void kernel_launch(void* const* d_in, const int* in_sizes, int n_in,
                              void* d_out, int out_size, void* d_ws, size_t ws_size,
                              hipStream_t stream) {
  const float* x = (const float*)d_in[0];
  float* out = (float*)d_out;

  short* pl0 = (short*)d_ws;                        // 64*81024 bf16
  short* pl1 = pl0 + (size_t)BC * PL;
  short* wb0 = pl1 + (size_t)BC * PL;               // 1024*1024
  short* wb1 = wb0 + (size_t)1024 * KD;             // total 24.9 MB

  prep_all<<<PREP_PLANE_BLOCKS + 1024, 256, 0, stream>>>(x, pl0, pl1, wb0, wb1);
  stft_gemm<<<NWG, 512, 0, stream>>>(pl0, pl1, wb0, wb1, out);
}

// Round 18
// 132.713 us; speedup vs baseline: 1.0325x; 1.0325x over previous
//
#include <hip/hip_runtime.h>

// ---------------- problem constants ----------------
#define B_     32
#define C_     2
#define L_     160000
#define HOP    512
#define PAD    1024
#define LPAD   162048            // L_ + 2*PAD
#define T_     313               // frames
#define BC     64                // B_*C_
#define M_     20032             // BC*T_
#define KCH    1025              // output channels per (real|imag)
#define OUT_HALF 20532800UL      // M_*KCH
#define PL     81024             // plane length per bc (LPAD/2)
#define KD     1024              // decimated K
#define NKT    32                // KD/32 K-tiles
#define NWG    1280              // 160*8 (24 dead blocks early-exit)
#define ZSTR   132               // epilogue zone row stride (words): 528B
#define Z1     8448              // zone-1 word offset: 64*132
#define PREP_PLANE_BLOCKS 2532   // prep grid split

typedef __attribute__((ext_vector_type(8))) short short8;
typedef __attribute__((ext_vector_type(4))) float f32x4;

static __device__ __forceinline__ short f2bf(float f) {
  union { float f; unsigned u; } v; v.f = f;
  unsigned u = v.u;
  unsigned r = (u + 0x7fffu + ((u >> 16) & 1u)) >> 16;  // RNE
  return (short)r;
}

// ---------------- fused prep: planes + weights in one launch ----------------
__global__ void prep_all(const float* __restrict__ x,
                         short* __restrict__ pl0, short* __restrict__ pl1,
                         short* __restrict__ wb0, short* __restrict__ wb1) {
  int b = blockIdx.x;
  if (b < PREP_PLANE_BLOCKS) {
    // ---- even/odd deinterleaved reflect-padded planes ----
    int v = b * 256 + threadIdx.x;                  // < 64*10128 = 648192
    int bc = v / 10128;
    int r  = v - bc * 10128;
    int p0 = r * 8;                                 // 8 p-positions -> 16 samples
    const float* src = x + (size_t)bc * L_;
    short8 e, o;
    if (r >= 64 && r <= 10000) {                    // fully interior
      int j0 = 16 * r - 1024;
      #pragma unroll
      for (int qq = 0; qq < 4; ++qq) {
        float4 f = *(const float4*)(src + j0 + qq * 4);
        e[qq * 2 + 0] = f2bf(f.x); o[qq * 2 + 0] = f2bf(f.y);
        e[qq * 2 + 1] = f2bf(f.z); o[qq * 2 + 1] = f2bf(f.w);
      }
    } else {
      #pragma unroll
      for (int u = 0; u < 16; ++u) {
        int j = 16 * r + u - 1024;
        j = j < 0 ? -j : j;
        j = j >= L_ ? 2 * L_ - 2 - j : j;
        short bb = f2bf(src[j]);
        if (u & 1) o[u >> 1] = bb; else e[u >> 1] = bb;
      }
    }
    *(short8*)&pl0[(size_t)bc * PL + p0] = e;
    *(short8*)&pl1[(size_t)bc * PL + p0] = o;
  } else {
    // ---- windowed DFT-1024 weights, interleaved re/im rows ----
    int id = (b - PREP_PLANE_BLOCKS) * 256 + threadIdx.x;  // < 262144
    int s   = id >> 17;
    int row = (id >> 7) & 1023;
    int n8  = (id & 127) * 8;
    int kp  = row >> 1, e = row & 1;
    short8 ov;
    #pragma unroll
    for (int u = 0; u < 8; ++u) {
      int n1 = n8 + u;
      float win = 0.5f - 0.5f * cosf((float)(2 * n1 + s) * 3.0679615757712823e-3f);
      float tw;
      if (e == 0)       tw = cosf((float)((n1 * kp) & 1023) * 6.1359231515425649e-3f);
      else if (kp == 0) tw = (n1 & 1) ? -1.0f : 1.0f;     // cos(pi*n1): re[512] row
      else              tw = -sinf((float)((n1 * kp) & 1023) * 6.1359231515425649e-3f);
      ov[u] = f2bf(win * tw);
    }
    short* wb = s ? wb1 : wb0;
    *(short8*)&wb[(size_t)row * KD + n8] = ov;
  }
}

// ---------------- GEMM: 128x128 tile, 512 thr, dual-plane acc, BK=32 ----------------
#define GLOAD16(g, l) __builtin_amdgcn_global_load_lds(                        \
    (const __attribute__((address_space(1))) void*)(g),                        \
    (__attribute__((address_space(3))) void*)(l), 16, 0, 0)

__global__ __launch_bounds__(512, 4) void stft_gemm(const short* __restrict__ pl0,
                                                    const short* __restrict__ pl1,
                                                    const short* __restrict__ wb0,
                                                    const short* __restrict__ wb1,
                                                    float* __restrict__ out) {
  // main loop: 2 buffers x (A0,A1,B0,B1 each [128][32] = 8KB) = 64KB
  // epilogue reuse: raw zones [2 planes][64 rows][132] fp32 = 67584 B
  __shared__ __align__(16) char lds[67584];
  const int tid  = threadIdx.x;
  const int lane = tid & 63;
  const int wid  = tid >> 6;          // 0..7

  // ---- XCD remap: 8 nt-blocks sharing an A-panel are consecutive ids with the
  // same id%8 -> same XCD -> A fetched ~once per panel; B (4MB) L2-resident.
  const int id = blockIdx.x;                   // 0..1279
  const int mt = (id & 7) * 20 + (id >> 6);    // 0..159
  if (mt >= 157) return;                       // dead-padded blocks: exit early
  const int nt = (id >> 3) & 7;
  const int M0 = mt * 128, N0 = nt * 128;

  // ---- staging: 1 instr per operand per plane; 512 threads cover [128][32] ----
  const int srow = tid >> 2;                                 // 0..127
  const int chunkSwz = ((tid & 3) ^ ((tid >> 3) & 3)) * 8;   // inverse-swizzled src
  const short* aP[2];
  const short* bP[2];
  {
    int m = M0 + srow; if (m > M_ - 1) m = M_ - 1;           // clamp (not stored)
    int bc = m / T_;
    int t  = m - bc * T_;
    size_t base = (size_t)bc * PL + (size_t)t * 256 + chunkSwz;
    aP[0] = pl0 + base;
    aP[1] = pl1 + base;
    size_t bb = (size_t)(N0 + srow) * KD + chunkSwz;
    bP[0] = wb0 + bb;
    bP[1] = wb1 + bb;
  }
  const int dstOff = tid * 16;   // linear LDS dest (waveBase + lane*16 invariant)

  // ---- fragment read offsets (proven conflict-free 64B-row XOR pattern) ----
  const int wr = wid >> 2, wc = wid & 3;    // 2m x 4n waves; per-wave 64x32
  const int fr = lane & 15;
  const int xorb = ((lane >> 4) * 16) ^ ((fr & 6) << 3);
  int afOff[2][4], bfOff[2][2];
  #pragma unroll
  for (int s = 0; s < 2; ++s) {
    #pragma unroll
    for (int i = 0; i < 4; ++i)
      afOff[s][i] = s * 8192 + (wr * 64 + i * 16 + fr) * 64 + xorb;
    #pragma unroll
    for (int j = 0; j < 2; ++j)
      bfOff[s][j] = 16384 + s * 8192 + (wc * 32 + j * 16 + fr) * 64 + xorb;
  }

  f32x4 acc[2][4][2];
  #pragma unroll
  for (int s = 0; s < 2; ++s)
    #pragma unroll
    for (int i = 0; i < 4; ++i)
      #pragma unroll
      for (int j = 0; j < 2; ++j) acc[s][i][j] = (f32x4){0.f, 0.f, 0.f, 0.f};

  // ---- prologue: stage kt=0 (A0,B0 then A1,B1 — order matters for vmcnt) ----
  GLOAD16(aP[0], lds + dstOff);
  GLOAD16(bP[0], lds + 16384 + dstOff);
  GLOAD16(aP[1], lds + 8192 + dstOff);
  GLOAD16(bP[1], lds + 24576 + dstOff);

  // ---- main loop: all 4 next-tile loads staged at s0; counted vmcnt ----
  // NO setprio: T5 is null on lockstep 2-phase structures (m190, r16 A/B).
  for (int kt = 0; kt < NKT; ++kt) {
    char* bufR = lds + (kt & 1) * 32768;
    char* bufW = lds + ((kt + 1) & 1) * 32768;
    const int kos = (kt + 1) * 32;
    const bool st = (kt < NKT - 1);

    // phase s=0
    asm volatile("s_waitcnt vmcnt(2)" ::: "memory");   // A0,B0(kt) landed
    __builtin_amdgcn_s_barrier();
    if (st) {
      GLOAD16(aP[0] + kos, bufW + dstOff);
      GLOAD16(bP[0] + kos, bufW + 16384 + dstOff);
      GLOAD16(aP[1] + kos, bufW + 8192 + dstOff);
      GLOAD16(bP[1] + kos, bufW + 24576 + dstOff);
    }
    short8 af0[4], bf0[2];
    #pragma unroll
    for (int i = 0; i < 4; ++i) af0[i] = *(const short8*)(bufR + afOff[0][i]);
    #pragma unroll
    for (int j = 0; j < 2; ++j) bf0[j] = *(const short8*)(bufR + bfOff[0][j]);
    #pragma unroll
    for (int i = 0; i < 4; ++i)
      #pragma unroll
      for (int j = 0; j < 2; ++j)
        acc[0][i][j] = __builtin_amdgcn_mfma_f32_16x16x32_bf16(af0[i], bf0[j],
                                                               acc[0][i][j], 0, 0, 0);

    // phase s=1 (pure read+MFMA; stage already issued)
    if (st) asm volatile("s_waitcnt vmcnt(4)" ::: "memory");  // A1,B1(kt) landed
    else    asm volatile("s_waitcnt vmcnt(0)" ::: "memory");
    __builtin_amdgcn_s_barrier();
    short8 af1[4], bf1[2];
    #pragma unroll
    for (int i = 0; i < 4; ++i) af1[i] = *(const short8*)(bufR + afOff[1][i]);
    #pragma unroll
    for (int j = 0; j < 2; ++j) bf1[j] = *(const short8*)(bufR + bfOff[1][j]);
    #pragma unroll
    for (int i = 0; i < 4; ++i)
      #pragma unroll
      for (int j = 0; j < 2; ++j)
        acc[1][i][j] = __builtin_amdgcn_mfma_f32_16x16x32_bf16(af1[i], bf1[j],
                                                               acc[1][i][j], 0, 0, 0);
  }

  // ---- epilogue v3 (r12-proven): raw-stage once per row-half, single combine ----
  // zone layout: Lf[pl*Z1 + row*ZSTR + col], col in [0,128): even=re, odd=im.
  float* Lf = (float*)lds;
  float* outI = out + OUT_HALF;
  const int q = lane;                               // 0..63 (local q index)
  const float ang = (float)(nt * 64 + q) * 3.0679615757712823e-3f;   // pi*k/1024
  const float tr = cosf(ang), sn = sinf(ang);       // t = tr - i*sn
  const int rgrp = (lane >> 4) << 2;

  __syncthreads();   // all main-loop LDS reads complete before reuse

  #pragma unroll
  for (int h = 0; h < 2; ++h) {
    if (wr == h) {   // owner waves stage raw acc for rows [h*64, h*64+64)
      #pragma unroll
      for (int pl = 0; pl < 2; ++pl)
        #pragma unroll
        for (int i = 0; i < 4; ++i)
          #pragma unroll
          for (int j = 0; j < 2; ++j)
            #pragma unroll
            for (int r = 0; r < 4; ++r)
              Lf[pl * Z1 + (i * 16 + rgrp + r) * ZSTR + wc * 32 + j * 16 + fr]
                 = acc[pl][i][j][r];
    }
    __syncthreads();
    // combine + store: lane = q, 8 rows per iteration across the 8 waves
    #pragma unroll
    for (int it = 0; it < 8; ++it) {
      int row = wid + it * 8;                       // 0..63
      int gm  = M0 + h * 64 + row;
      if (gm < M_) {
        float2 y0 = *(const float2*)&Lf[row * ZSTR + 2 * q];
        float2 y1 = *(const float2*)&Lf[Z1 + row * ZSTR + 2 * q];
        float ur = tr * y1.x + sn * y1.y;           // Re(t*Y1)
        float ui = tr * y1.y - sn * y1.x;           // Im(t*Y1)
        size_t rb = (size_t)gm * KCH;
        if (nt == 0 && q == 0) {
          // cols 0,1 are the special real rows: Y[0] and Y[512]
          out [rb + 0]    = y0.x + y1.x;            // X[0] = Y0[0]+Y1[0]
          outI[rb + 0]    = 0.f;
          out [rb + 1024] = y0.x - y1.x;            // X[1024] = Y0[0]-Y1[0]
          outI[rb + 1024] = 0.f;
          out [rb + 512]  = y0.y;                   // X[512] = Y0[512] - i*Y1[512]
          outI[rb + 512]  = -y1.y;
        } else {
          int kq = nt * 64 + q;
          out [rb + kq]        = y0.x + ur;         // X[k]
          outI[rb + kq]        = y0.y + ui;
          out [rb + 1024 - kq] = y0.x - ur;         // X[1024-k] (conj pair)
          outI[rb + 1024 - kq] = -(y0.y - ui);
        }
      }
    }
    __syncthreads();   // zones reused by next row-half
  }
}

// ---------------- launcher ----------------
extern "C" void kernel_launch(void* const* d_in, const int* in_sizes, int n_in,
                              void* d_out, int out_size, void* d_ws, size_t ws_size,
                              hipStream_t stream) {
  const float* x = (const float*)d_in[0];
  float* out = (float*)d_out;

  short* pl0 = (short*)d_ws;                        // 64*81024 bf16
  short* pl1 = pl0 + (size_t)BC * PL;
  short* wb0 = pl1 + (size_t)BC * PL;               // 1024*1024
  short* wb1 = wb0 + (size_t)1024 * KD;             // total 24.9 MB

  prep_all<<<PREP_PLANE_BLOCKS + 1024, 256, 0, stream>>>(x, pl0, pl1, wb0, wb1);
  stft_gemm<<<NWG, 512, 0, stream>>>(pl0, pl1, wb0, wb1, out);
}